// Round 10
// baseline (266.340 us; speedup 1.0000x reference)
//
#include <hip/hip_runtime.h>

static constexpr int    kN = 200000;
static constexpr int    kC = 20;
static constexpr int    kP = 256;
static constexpr int    kM = 400000;
static constexpr int    kThreshPts = 100;
static constexpr int    kRowCap = 2048;                  // 12 sigma above mean 1562
static constexpr int    kLWords = kN / 32;               // 6250 words per row
static constexpr int    kF4Total = kN * kC / 4;          // 1,000,000 float4 of logits/probs
static constexpr int    kSlices = 16;                    // expand blocks per row
static constexpr int    kF4PerSlice = kN / 4 / kSlices;  // 3125

// output layout (float elements)
static constexpr size_t OFF_SCORES  = 0;
static constexpr size_t OFF_MASKS   = 256;
static constexpr size_t OFF_CLASSES = OFF_MASKS + (size_t)kP * kN;   // 51200256
static constexpr size_t OFF_BIAS    = OFF_CLASSES + 256;             // 51200512
static constexpr size_t OFF_PROBS   = OFF_BIAS + 3 * (size_t)kN;     // 51800512

// workspace layout (bytes)
static constexpr size_t WS_CURSOR = 0;                               // int[256]
static constexpr size_t WS_ROWVAL = 1024;                            // float[256]
static constexpr size_t WS_SEG    = 2048;                            // int[kN]
static constexpr size_t WS_ROWBUF = WS_SEG + (size_t)kN * 4;         // int[256*2048]
static constexpr size_t WS_GBITS  = WS_ROWBUF + (size_t)kP * kRowCap * 4; // uint[256*6250]

// K1: LDS-transposed softmax. Global I/O fully coalesced.
__global__ void __launch_bounds__(256)
k_softmax(const float* __restrict__ logit,
          const float* __restrict__ bias,
          float* __restrict__ out,
          int* __restrict__ seg,
          int* __restrict__ cursor) {
    __shared__ float lds[256][21];                       // pad breaks stride-20
    int t = threadIdx.x;
    int gbase = blockIdx.x * 1280;                       // block's float4 range

#pragma unroll
    for (int i = 0; i < 5; i++) {
        int g = gbase + i * 256 + t;
        if (g < kF4Total) {
            float4 v4 = ((const float4*)logit)[g];
            int lf = (g - gbase) * 4;
            float vv[4] = {v4.x, v4.y, v4.z, v4.w};
#pragma unroll
            for (int k = 0; k < 4; k++) {
                int fl = lf + k;
                lds[fl / kC][fl % kC] = vv[k];
            }
        }
    }
    if (blockIdx.x == 0) cursor[t] = 0;
    int tid = blockIdx.x * 256 + t;
    if (tid < 150000) {
        ((float4*)(out + OFF_BIAS))[tid] = ((const float4*)bias)[tid];
    }
    __syncthreads();

    bool valid = tid < kN;
    float v[kC];
    if (valid) {
#pragma unroll
        for (int i = 0; i < kC; i++) v[i] = lds[t][i];
        float m = v[0]; int arg = 0;
#pragma unroll
        for (int i = 1; i < kC; i++) if (v[i] > m) { m = v[i]; arg = i; }  // first max
        float ssum = 0.0f;
#pragma unroll
        for (int i = 0; i < kC; i++) { v[i] = __expf(v[i] - m); ssum += v[i]; }
        float inv = 1.0f / ssum;
#pragma unroll
        for (int i = 0; i < kC; i++) v[i] *= inv;
        seg[tid] = arg;
    }
    __syncthreads();
    if (valid) {
#pragma unroll
        for (int i = 0; i < kC; i++) lds[t][i] = v[i];
    }
    __syncthreads();

    float* probs = out + OFF_PROBS;
#pragma unroll
    for (int i = 0; i < 5; i++) {
        int g = gbase + i * 256 + t;
        if (g < kF4Total) {
            int lf = (g - gbase) * 4;
            float4 o;
            o.x = lds[(lf    ) / kC][(lf    ) % kC];
            o.y = lds[(lf + 1) / kC][(lf + 1) % kC];
            o.z = lds[(lf + 2) / kC][(lf + 2) % kC];
            o.w = lds[(lf + 3) / kC][(lf + 3) % kC];
            ((float4*)probs)[g] = o;
        }
    }
}

// K2: bucket pairs by proposal. LDS histogram -> one global atomic per
// (block,row) -> plain stores.
__global__ void k_bucket(const int* __restrict__ prop,
                         const int* __restrict__ pt,
                         int* __restrict__ cursor,
                         int* __restrict__ rowbuf) {
    __shared__ int s_cnt[kP];
    __shared__ int s_off[kP];
    int t = threadIdx.x;                                 // 1024 threads
    if (t < kP) s_cnt[t] = 0;
    __syncthreads();
    int base = blockIdx.x * 4096;
    int pv[4], nv[4], slot[4];
    bool val[4];
#pragma unroll
    for (int j = 0; j < 4; j++) {
        int idx = base + j * 1024 + t;
        val[j] = idx < kM;
        if (val[j]) {
            pv[j]   = prop[idx];
            nv[j]   = pt[idx];
            slot[j] = atomicAdd(&s_cnt[pv[j]], 1);       // LDS atomic
        }
    }
    __syncthreads();
    if (t < kP) s_off[t] = s_cnt[t] ? atomicAdd(&cursor[t], s_cnt[t]) : 0;
    __syncthreads();
#pragma unroll
    for (int j = 0; j < 4; j++) {
        if (val[j]) {
            int dst = s_off[pv[j]] + slot[j];
            if (dst < kRowCap) rowbuf[pv[j] * kRowCap + dst] = nv[j];
        }
    }
}

// K3: one block (1024 thr) per proposal. Build LDS bits: count/rep/cls/flag,
// claim-dedupe score gather, rebuild, export bits to global + rowval table.
__global__ void __launch_bounds__(1024)
k_meta(const int* __restrict__ rowbuf,
       const int* __restrict__ cursor,
       const int* __restrict__ seg,
       unsigned int* __restrict__ gbits,
       float* __restrict__ rowval,
       float* __restrict__ out) {
    __shared__ unsigned int lbits[kLWords];              // 25 KB
    __shared__ int   s_redc[16];
    __shared__ int   s_redm[16];
    __shared__ float s_redf[16];
    __shared__ int   s_cls;
    __shared__ float s_fv;

    int p = blockIdx.x;
    int t = threadIdx.x;
    const float* probs = out + OFF_PROBS;

    for (int i = t; i < kLWords; i += 1024) lbits[i] = 0;
    int len = cursor[p];
    if (len > kRowCap) len = kRowCap;
    __syncthreads();

    int mymin = 0x7fffffff;
    const int* rb = rowbuf + p * kRowCap;
    for (int i = t; i < len; i += 1024) {
        int n = rb[i];
        atomicOr(&lbits[(unsigned)n >> 5], 1u << (n & 31));
        mymin = n < mymin ? n : mymin;
    }
    __syncthreads();

    int cnt = 0;
    for (int i = t; i < kLWords; i += 1024) cnt += __popc(lbits[i]);
    for (int off = 32; off; off >>= 1) {
        cnt += __shfl_down(cnt, off);
        int om = __shfl_down(mymin, off);
        mymin = om < mymin ? om : mymin;
    }
    if ((t & 63) == 0) { s_redc[t >> 6] = cnt; s_redm[t >> 6] = mymin; }
    __syncthreads();
    if (t == 0) {
        int tot = 0, mn = 0x7fffffff;
        for (int i = 0; i < 16; i++) {
            tot += s_redc[i];
            mn = s_redm[i] < mn ? s_redm[i] : mn;
        }
        int r = mn < 0 ? 0 : (mn > kN - 1 ? kN - 1 : mn);   // clip (empty -> clamp)
        int c = seg[r];
        bool fl = tot > kThreshPts;
        s_cls = c;
        s_fv  = fl ? 1.0f : 0.0f;
        s_redc[0] = tot;
        rowval[p] = fl ? 1.0f : 0.0f;
        out[OFF_CLASSES + p] = fl ? (float)c : -1.0f;
    }
    __syncthreads();
    int   tot = s_redc[0];
    float fv  = s_fv;
    int   c   = s_cls;

    // claim-dedupe gather (destroys bits; exact dedupe via old-bit test)
    float s = 0.0f;
    for (int i = t; i < len; i += 1024) {
        int n = rb[i];
        unsigned int bit = 1u << (n & 31);
        unsigned int old = atomicAnd(&lbits[(unsigned)n >> 5], ~bit);
        if (old & bit) s += probs[(size_t)n * kC + c];
    }
    for (int off = 32; off; off >>= 1) s += __shfl_down(s, off);
    if ((t & 63) == 0) s_redf[t >> 6] = s;
    __syncthreads();
    if (t == 0) {
        float stot = 0.0f;
        for (int i = 0; i < 16; i++) stot += s_redf[i];
        float denom = (float)(tot > 1 ? tot : 1);
        out[OFF_SCORES + p] = (fv != 0.0f) ? stot / denom : 0.0f;
    }

    // rebuild (idempotent)
    for (int i = t; i < len; i += 1024) {
        int n = rb[i];
        atomicOr(&lbits[(unsigned)n >> 5], 1u << (n & 31));
    }
    __syncthreads();

    // export LDS bits -> global, coalesced
    unsigned int* grow = gbits + (size_t)p * kLWords;
    for (int i = t; i < kLWords; i += 1024) grow[i] = lbits[i];
}

// K4: fillBuffer-clone expansion: block-uniform row, regular cached stores,
// one L3-hot word read per 8 float4 stores. NO nontemporal flag.
__global__ void __launch_bounds__(256)
k_expand(const unsigned int* __restrict__ gbits,
         const float* __restrict__ rowval,
         float* __restrict__ masks) {
    int p = blockIdx.x >> 4;                             // row (uniform per block)
    int q = blockIdx.x & 15;                             // slice
    float fv = rowval[p];
    const unsigned int* row = gbits + (size_t)p * kLWords;
    float4* mrow = (float4*)masks + (size_t)p * (kN / 4);
    int fbase = q * kF4PerSlice;
    int fend  = fbase + kF4PerSlice;
    for (int f = fbase + threadIdx.x; f < fend; f += 256) {  // ~12 iters
        unsigned int word = row[f >> 3];
        unsigned int b    = (word >> (((unsigned)f & 7u) * 4u)) & 0xFu;
        float4 o;
        o.x = (b & 1u) ? fv : 0.0f;
        o.y = (b & 2u) ? fv : 0.0f;
        o.z = (b & 4u) ? fv : 0.0f;
        o.w = (b & 8u) ? fv : 0.0f;
        mrow[f] = o;
    }
}

extern "C" void kernel_launch(void* const* d_in, const int* in_sizes, int n_in,
                              void* d_out, int out_size, void* d_ws, size_t ws_size,
                              hipStream_t stream) {
    const float* logit = (const float*)d_in[0];
    const float* bias  = (const float*)d_in[1];
    // d_in[2] = coord: dead code in the reference (center_pred unused)
    const int* prop = (const int*)d_in[3];
    const int* pt   = (const int*)d_in[4];
    float* out = (float*)d_out;
    char*  ws  = (char*)d_ws;

    int*          cursor = (int*)(ws + WS_CURSOR);
    float*        rowval = (float*)(ws + WS_ROWVAL);
    int*          seg    = (int*)(ws + WS_SEG);
    int*          rowbuf = (int*)(ws + WS_ROWBUF);
    unsigned int* gbits  = (unsigned int*)(ws + WS_GBITS);

    k_softmax<<<(kN + 255) / 256, 256, 0, stream>>>(logit, bias, out, seg, cursor);
    k_bucket<<<(kM + 4095) / 4096, 1024, 0, stream>>>(prop, pt, cursor, rowbuf);
    k_meta<<<kP, 1024, 0, stream>>>(rowbuf, cursor, seg, gbits, rowval, out);
    k_expand<<<kP * kSlices, 256, 0, stream>>>(gbits, rowval, out + OFF_MASKS);
}

// Round 11
// 262.964 us; speedup vs baseline: 1.0128x; 1.0128x over previous
//
#include <hip/hip_runtime.h>

static constexpr int    kN = 200000;
static constexpr int    kC = 20;
static constexpr int    kP = 256;
static constexpr int    kM = 400000;
static constexpr int    kThreshPts = 100;
static constexpr int    kRowCap = 2048;                  // 12 sigma above mean 1562
static constexpr int    kLWords = kN / 32;               // 6250 words per row
static constexpr int    kF4Total = kN * kC / 4;          // 1,000,000 float4 of logits/probs

// output layout (float elements)
static constexpr size_t OFF_SCORES  = 0;
static constexpr size_t OFF_MASKS   = 256;
static constexpr size_t OFF_CLASSES = OFF_MASKS + (size_t)kP * kN;   // 51200256
static constexpr size_t OFF_BIAS    = OFF_CLASSES + 256;             // 51200512
static constexpr size_t OFF_PROBS   = OFF_BIAS + 3 * (size_t)kN;     // 51800512

// workspace layout (bytes)
static constexpr size_t WS_CURSOR = 0;                               // int[256]
static constexpr size_t WS_ROWVAL = 1024;                            // float[256]
static constexpr size_t WS_SEG    = 2048;                            // int[kN]
static constexpr size_t WS_ROWBUF = WS_SEG + (size_t)kN * 4;         // int[256*2048]

// K0: pure fill-clone — zero the entire mask region. No loads, no decode.
__global__ void __launch_bounds__(256)
k_zero(float4* __restrict__ masks) {
    const size_t total = (size_t)kP * kN / 4;            // 12.8M float4
    size_t stride = (size_t)gridDim.x * 256;
    float4 z = make_float4(0.0f, 0.0f, 0.0f, 0.0f);
    for (size_t f = (size_t)blockIdx.x * 256 + threadIdx.x; f < total; f += stride)
        masks[f] = z;
}

// K1: LDS-transposed softmax. Global I/O fully coalesced.
__global__ void __launch_bounds__(256)
k_softmax(const float* __restrict__ logit,
          const float* __restrict__ bias,
          float* __restrict__ out,
          int* __restrict__ seg,
          int* __restrict__ cursor) {
    __shared__ float lds[256][21];                       // pad breaks stride-20
    int t = threadIdx.x;
    int gbase = blockIdx.x * 1280;                       // block's float4 range

#pragma unroll
    for (int i = 0; i < 5; i++) {
        int g = gbase + i * 256 + t;
        if (g < kF4Total) {
            float4 v4 = ((const float4*)logit)[g];
            int lf = (g - gbase) * 4;
            float vv[4] = {v4.x, v4.y, v4.z, v4.w};
#pragma unroll
            for (int k = 0; k < 4; k++) {
                int fl = lf + k;
                lds[fl / kC][fl % kC] = vv[k];
            }
        }
    }
    if (blockIdx.x == 0) cursor[t] = 0;
    int tid = blockIdx.x * 256 + t;
    if (tid < 150000) {
        ((float4*)(out + OFF_BIAS))[tid] = ((const float4*)bias)[tid];
    }
    __syncthreads();

    bool valid = tid < kN;
    float v[kC];
    if (valid) {
#pragma unroll
        for (int i = 0; i < kC; i++) v[i] = lds[t][i];
        float m = v[0]; int arg = 0;
#pragma unroll
        for (int i = 1; i < kC; i++) if (v[i] > m) { m = v[i]; arg = i; }  // first max
        float ssum = 0.0f;
#pragma unroll
        for (int i = 0; i < kC; i++) { v[i] = __expf(v[i] - m); ssum += v[i]; }
        float inv = 1.0f / ssum;
#pragma unroll
        for (int i = 0; i < kC; i++) v[i] *= inv;
        seg[tid] = arg;
    }
    __syncthreads();
    if (valid) {
#pragma unroll
        for (int i = 0; i < kC; i++) lds[t][i] = v[i];
    }
    __syncthreads();

    float* probs = out + OFF_PROBS;
#pragma unroll
    for (int i = 0; i < 5; i++) {
        int g = gbase + i * 256 + t;
        if (g < kF4Total) {
            int lf = (g - gbase) * 4;
            float4 o;
            o.x = lds[(lf    ) / kC][(lf    ) % kC];
            o.y = lds[(lf + 1) / kC][(lf + 1) % kC];
            o.z = lds[(lf + 2) / kC][(lf + 2) % kC];
            o.w = lds[(lf + 3) / kC][(lf + 3) % kC];
            ((float4*)probs)[g] = o;
        }
    }
}

// K2: bucket pairs by proposal. LDS histogram -> one global atomic per
// (block,row) -> plain stores.
__global__ void k_bucket(const int* __restrict__ prop,
                         const int* __restrict__ pt,
                         int* __restrict__ cursor,
                         int* __restrict__ rowbuf) {
    __shared__ int s_cnt[kP];
    __shared__ int s_off[kP];
    int t = threadIdx.x;                                 // 1024 threads
    if (t < kP) s_cnt[t] = 0;
    __syncthreads();
    int base = blockIdx.x * 4096;
    int pv[4], nv[4], slot[4];
    bool val[4];
#pragma unroll
    for (int j = 0; j < 4; j++) {
        int idx = base + j * 1024 + t;
        val[j] = idx < kM;
        if (val[j]) {
            pv[j]   = prop[idx];
            nv[j]   = pt[idx];
            slot[j] = atomicAdd(&s_cnt[pv[j]], 1);       // LDS atomic
        }
    }
    __syncthreads();
    if (t < kP) s_off[t] = s_cnt[t] ? atomicAdd(&cursor[t], s_cnt[t]) : 0;
    __syncthreads();
#pragma unroll
    for (int j = 0; j < 4; j++) {
        if (val[j]) {
            int dst = s_off[pv[j]] + slot[j];
            if (dst < kRowCap) rowbuf[pv[j] * kRowCap + dst] = nv[j];
        }
    }
}

// K3: one block (1024 thr) per proposal. LDS bits: dedupe count, rep, cls,
// flag, claim-dedupe score gather. Writes scores/classes/rowval only.
__global__ void __launch_bounds__(1024)
k_meta(const int* __restrict__ rowbuf,
       const int* __restrict__ cursor,
       const int* __restrict__ seg,
       float* __restrict__ rowval,
       float* __restrict__ out) {
    __shared__ unsigned int lbits[kLWords];              // 25 KB
    __shared__ int   s_redc[16];
    __shared__ int   s_redm[16];
    __shared__ float s_redf[16];
    __shared__ int   s_cls;
    __shared__ float s_fv;

    int p = blockIdx.x;
    int t = threadIdx.x;
    const float* probs = out + OFF_PROBS;

    for (int i = t; i < kLWords; i += 1024) lbits[i] = 0;
    int len = cursor[p];
    if (len > kRowCap) len = kRowCap;
    __syncthreads();

    int mymin = 0x7fffffff;
    const int* rb = rowbuf + p * kRowCap;
    for (int i = t; i < len; i += 1024) {
        int n = rb[i];
        atomicOr(&lbits[(unsigned)n >> 5], 1u << (n & 31));
        mymin = n < mymin ? n : mymin;
    }
    __syncthreads();

    int cnt = 0;
    for (int i = t; i < kLWords; i += 1024) cnt += __popc(lbits[i]);
    for (int off = 32; off; off >>= 1) {
        cnt += __shfl_down(cnt, off);
        int om = __shfl_down(mymin, off);
        mymin = om < mymin ? om : mymin;
    }
    if ((t & 63) == 0) { s_redc[t >> 6] = cnt; s_redm[t >> 6] = mymin; }
    __syncthreads();
    if (t == 0) {
        int tot = 0, mn = 0x7fffffff;
        for (int i = 0; i < 16; i++) {
            tot += s_redc[i];
            mn = s_redm[i] < mn ? s_redm[i] : mn;
        }
        int r = mn < 0 ? 0 : (mn > kN - 1 ? kN - 1 : mn);   // clip (empty -> clamp)
        int c = seg[r];
        bool fl = tot > kThreshPts;
        s_cls = c;
        s_fv  = fl ? 1.0f : 0.0f;
        s_redc[0] = tot;
        rowval[p] = fl ? 1.0f : 0.0f;
        out[OFF_CLASSES + p] = fl ? (float)c : -1.0f;
    }
    __syncthreads();
    int   tot = s_redc[0];
    float fv  = s_fv;
    int   c   = s_cls;

    // claim-dedupe gather (exact dedupe via old-bit test)
    float s = 0.0f;
    for (int i = t; i < len; i += 1024) {
        int n = rb[i];
        unsigned int bit = 1u << (n & 31);
        unsigned int old = atomicAnd(&lbits[(unsigned)n >> 5], ~bit);
        if (old & bit) s += probs[(size_t)n * kC + c];
    }
    for (int off = 32; off; off >>= 1) s += __shfl_down(s, off);
    if ((t & 63) == 0) s_redf[t >> 6] = s;
    __syncthreads();
    if (t == 0) {
        float stot = 0.0f;
        for (int i = 0; i < 16; i++) stot += s_redf[i];
        float denom = (float)(tot > 1 ? tot : 1);
        out[OFF_SCORES + p] = (fv != 0.0f) ? stot / denom : 0.0f;
    }
}

// K4: scatter the ~400k set positions (duplicates store same value: benign).
__global__ void __launch_bounds__(1024)
k_set(const int* __restrict__ rowbuf,
      const int* __restrict__ cursor,
      const float* __restrict__ rowval,
      float* __restrict__ masks) {
    int p = blockIdx.x;
    float fv = rowval[p];
    if (fv == 0.0f) return;                              // row stays all-zero
    int len = cursor[p];
    if (len > kRowCap) len = kRowCap;
    float* mrow = masks + (size_t)p * kN;
    const int* rb = rowbuf + p * kRowCap;
    for (int i = threadIdx.x; i < len; i += 1024)
        mrow[rb[i]] = fv;
}

extern "C" void kernel_launch(void* const* d_in, const int* in_sizes, int n_in,
                              void* d_out, int out_size, void* d_ws, size_t ws_size,
                              hipStream_t stream) {
    const float* logit = (const float*)d_in[0];
    const float* bias  = (const float*)d_in[1];
    // d_in[2] = coord: dead code in the reference (center_pred unused)
    const int* prop = (const int*)d_in[3];
    const int* pt   = (const int*)d_in[4];
    float* out = (float*)d_out;
    char*  ws  = (char*)d_ws;

    int*   cursor = (int*)(ws + WS_CURSOR);
    float* rowval = (float*)(ws + WS_ROWVAL);
    int*   seg    = (int*)(ws + WS_SEG);
    int*   rowbuf = (int*)(ws + WS_ROWBUF);

    k_zero<<<1024, 256, 0, stream>>>((float4*)(out + OFF_MASKS));
    k_softmax<<<(kN + 255) / 256, 256, 0, stream>>>(logit, bias, out, seg, cursor);
    k_bucket<<<(kM + 4095) / 4096, 1024, 0, stream>>>(prop, pt, cursor, rowbuf);
    k_meta<<<kP, 1024, 0, stream>>>(rowbuf, cursor, seg, rowval, out);
    k_set<<<kP, 1024, 0, stream>>>(rowbuf, cursor, rowval, out + OFF_MASKS);
}